// Round 20
// baseline (134.125 us; speedup 1.0000x reference)
//
#include <hip/hip_runtime.h>
#include <math.h>

#define NS 4
#define HDIM 1024
#define DDIM 4096           // NS*HDIM
#define TOK_B 8             // tokens per block (fused kernel)
#define KCH 256             // K extent per chunk; 16 chunks cover K=4096
#define NCH 16
#define NBUF 4
#define HC_EPS_F 1e-6f
#define NORM_EPS_F 1e-6f

typedef __attribute__((ext_vector_type(8))) short short8;
typedef __attribute__((ext_vector_type(4))) float f32x4;

__device__ __forceinline__ float frcp(float v) { return __builtin_amdgcn_rcpf(v); }

__device__ __forceinline__ void gload_lds16(const float* g, float* l) {
  __builtin_amdgcn_global_load_lds(
      (const __attribute__((address_space(1))) void*)g,
      (__attribute__((address_space(3))) void*)l, 16, 0, 0);
}

// fp32 -> bf16 hi (truncate) + lo (residual). 3-term MFMA ~ fp32 accuracy.
#define CVT_PAIR(j, f0, f1)                                                     \
  { unsigned p0 = __float_as_uint(f0), p1 = __float_as_uint(f1);                \
    H.u[j] = (p1 & 0xFFFF0000u) | (p0 >> 16);                                   \
    unsigned q0 = __float_as_uint((f0) - __uint_as_float(p0 & 0xFFFF0000u));    \
    unsigned q1 = __float_as_uint((f1) - __uint_as_float(p1 & 0xFFFF0000u));    \
    L.u[j] = (q1 & 0xFFFF0000u) | (q0 >> 16); }

__device__ __forceinline__ void cvt_hl(const float4 a, const float4 b,
                                       short8& hi, short8& lo) {
  union { unsigned u[4]; short8 s; } H, L;
  CVT_PAIR(0, a.x, a.y)
  CVT_PAIR(1, a.z, a.w)
  CVT_PAIR(2, b.x, b.y)
  CVT_PAIR(3, b.z, b.w)
  hi = H.s; lo = L.s;
}

// ============ K0: hc_fn fp32 -> bf16 hi/lo (once; B is block-invariant). ============
__launch_bounds__(256, 4)
__global__ void mhc_convb(const float* __restrict__ hc_fn,
                          unsigned short* __restrict__ bh,
                          unsigned short* __restrict__ bl) {
  const int g = blockIdx.x * 256 + threadIdx.x;     // float4 index, < 24576
  const float4 v = ((const float4*)hc_fn)[g];
  ushort4 h, l;
  unsigned p;
  p = __float_as_uint(v.x); h.x = p >> 16; l.x = __float_as_uint(v.x - __uint_as_float(p & 0xFFFF0000u)) >> 16;
  p = __float_as_uint(v.y); h.y = p >> 16; l.y = __float_as_uint(v.y - __uint_as_float(p & 0xFFFF0000u)) >> 16;
  p = __float_as_uint(v.z); h.z = p >> 16; l.z = __float_as_uint(v.z - __uint_as_float(p & 0xFFFF0000u)) >> 16;
  p = __float_as_uint(v.w); h.w = p >> 16; l.w = __float_as_uint(v.w - __uint_as_float(p & 0xFFFF0000u)) >> 16;
  ((ushort4*)bh)[g] = h;
  ((ushort4*)bl)[g] = l;
}

// ============ K1: FUSED dots + sinkhorn, counted-vmcnt 4-buffer pipeline (T4). ============
// Per iter: vmcnt(2) [chunk kc + B(kc) ready; chunks kc+1,kc+2 in flight] -> s_barrier
// -> compute(kc) [ds_read + MFMA only] -> load B(kc+1) regs -> STAGE(kc+3).
// One barrier/chunk; vmcnt NEVER drains to 0 in the main loop (T4, m218).
__launch_bounds__(256, 2)
__global__ void mhc_fused(const float* __restrict__ x,
                          const unsigned short* __restrict__ bh,
                          const unsigned short* __restrict__ bl,
                          const float* __restrict__ hc_scale,
                          const float* __restrict__ hc_base,
                          float* __restrict__ gates, int ntok) {
  __shared__ float xs[NBUF][TOK_B * KCH];  // 4 x 8 KB ring
  __shared__ float wsl[4][TOK_B][25];      // per-kh partials: 3.2 KB
  const int tid  = threadIdx.x;
  const int lane = tid & 63;
  const int wave = tid >> 6;
  const long long tok0 = (long long)blockIdx.x * TOK_B;

  // stage chunk kcn into ring buffer d (2 gloads/thread = 8 KB/block):
  // linear LDS dest; SOURCE col4 ^= token (both-sides swizzle, rule #21)
#define STAGE(d, kcn)                                                           \
  {                                                                             \
    _Pragma("unroll")                                                           \
    for (int c = 0; c < 2; ++c) {                                               \
      const int S = c * 256 + wave * 64;          /* float4 slot base */        \
      const int t = S >> 6;                       /* token row 0..7 */          \
      const int c4src = lane ^ t;                                               \
      gload_lds16(x + (tok0 + t) * DDIM + (kcn) * KCH + c4src * 4,              \
                  &xs[d][(size_t)S * 4]);                                       \
    }                                                                           \
  }

  const int kh   = wave;               // K quarter of each chunk (64 floats)
  const int row  = lane & 15;          // A row (dup token row&7) / B col (m)
  const int trow = row & 7;            // actual token row
  const int ks   = lane >> 4;          // k-slice (8 elems)

  const unsigned short* bp0h = bh + (long long)row * DDIM + kh * 64 + ks * 8;
  const unsigned short* bp0l = bl + (long long)row * DDIM + kh * 64 + ks * 8;
  const int fr1c = (row < 8) ? (16 + row) : 23;
  const unsigned short* bp1h = bh + (long long)fr1c * DDIM + kh * 64 + ks * 8;
  const unsigned short* bp1l = bl + (long long)fr1c * DDIM + kh * 64 + ks * 8;
  const bool v1 = (row < 8);
  const short8 z8 = {0, 0, 0, 0, 0, 0, 0, 0};

  f32x4 acc0 = {0.f, 0.f, 0.f, 0.f};
  f32x4 acc1 = {0.f, 0.f, 0.f, 0.f};
  float ssq = 0.f;

  // B register double-buffer: named sets (rule #20), loaded 1 chunk ahead
  short8 BA0h, BA0l, BA1h, BA1l, BA2h, BA2l, BA3h, BA3l;
  short8 BB0h, BB0l, BB1h, BB1l, BB2h, BB2l, BB3h, BB3l;

#define LOADB(P, kcn)                                                           \
  P##0h = *(const short8*)(bp0h + (kcn) * KCH);                                 \
  P##0l = *(const short8*)(bp0l + (kcn) * KCH);                                 \
  P##1h = v1 ? *(const short8*)(bp1h + (kcn) * KCH) : z8;                       \
  P##1l = v1 ? *(const short8*)(bp1l + (kcn) * KCH) : z8;                       \
  P##2h = *(const short8*)(bp0h + (kcn) * KCH + 32);                            \
  P##2l = *(const short8*)(bp0l + (kcn) * KCH + 32);                            \
  P##3h = v1 ? *(const short8*)(bp1h + (kcn) * KCH + 32) : z8;                  \
  P##3l = v1 ? *(const short8*)(bp1l + (kcn) * KCH + 32) : z8;

#define KSTEP(arow, s, BH0, BL0, BH1, BL1)                                      \
  {                                                                             \
    const int c4 = kh * 16 + (s) * 8 + ks * 2;                                  \
    const float4 a0 = *(const float4*)((arow) + (size_t)((c4) ^ trow) * 4);     \
    const float4 a1 = *(const float4*)((arow) + (size_t)((c4 + 1) ^ trow) * 4); \
    ssq = fmaf(a0.x, a0.x, fmaf(a0.y, a0.y, fmaf(a0.z, a0.z, fmaf(a0.w, a0.w, ssq)))); \
    ssq = fmaf(a1.x, a1.x, fmaf(a1.y, a1.y, fmaf(a1.z, a1.z, fmaf(a1.w, a1.w, ssq)))); \
    short8 ahi, alo;                                                            \
    cvt_hl(a0, a1, ahi, alo);                                                   \
    acc0 = __builtin_amdgcn_mfma_f32_16x16x32_bf16(ahi, BH0, acc0, 0, 0, 0);    \
    acc1 = __builtin_amdgcn_mfma_f32_16x16x32_bf16(ahi, BH1, acc1, 0, 0, 0);    \
    acc0 = __builtin_amdgcn_mfma_f32_16x16x32_bf16(ahi, BL0, acc0, 0, 0, 0);    \
    acc1 = __builtin_amdgcn_mfma_f32_16x16x32_bf16(ahi, BL1, acc1, 0, 0, 0);    \
    acc0 = __builtin_amdgcn_mfma_f32_16x16x32_bf16(alo, BH0, acc0, 0, 0, 0);    \
    acc1 = __builtin_amdgcn_mfma_f32_16x16x32_bf16(alo, BH1, acc1, 0, 0, 0);    \
  }

// One pipeline iteration. VM is a literal; DO_B/DO_S compile-time 0/1.
#define ITER(kc, SC, SN, VM, DO_B, DO_S)                                        \
  {                                                                             \
    asm volatile("s_waitcnt vmcnt(" #VM ")" ::: "memory");                      \
    __builtin_amdgcn_sched_barrier(0);                                          \
    __builtin_amdgcn_s_barrier();                                               \
    __builtin_amdgcn_sched_barrier(0);                                          \
    const float* arow = xs[(kc) & 3] + (size_t)trow * KCH;                      \
    KSTEP(arow, 0, SC##0h, SC##0l, SC##1h, SC##1l)                              \
    KSTEP(arow, 1, SC##2h, SC##2l, SC##3h, SC##3l)                              \
    if (DO_B) { LOADB(SN, (kc) + 1) }                                           \
    if (DO_S) STAGE(((kc) + 3) & 3, (kc) + 3)                                   \
  }

  // ---- prologue: stages 0,1 ; B(0) ; stage 2  (B(0) older than stage(2)) ----
  STAGE(0, 0)
  STAGE(1, 1)
  LOADB(BA, 0)
  STAGE(2, 2)

  // ---- 16 chunks, fully unrolled; vmcnt(2) main loop, vmcnt(0) tail ----
  ITER(0,  BA, BB, 2, 1, 1)
  ITER(1,  BB, BA, 2, 1, 1)
  ITER(2,  BA, BB, 2, 1, 1)
  ITER(3,  BB, BA, 2, 1, 1)
  ITER(4,  BA, BB, 2, 1, 1)
  ITER(5,  BB, BA, 2, 1, 1)
  ITER(6,  BA, BB, 2, 1, 1)
  ITER(7,  BB, BA, 2, 1, 1)
  ITER(8,  BA, BB, 2, 1, 1)
  ITER(9,  BB, BA, 2, 1, 1)
  ITER(10, BA, BB, 2, 1, 1)
  ITER(11, BB, BA, 2, 1, 1)
  ITER(12, BA, BB, 2, 1, 1)
  ITER(13, BB, BA, 2, 1, 0)
  ITER(14, BA, BB, 0, 1, 0)
  ITER(15, BB, BA, 0, 0, 0)

#undef ITER
#undef KSTEP
#undef LOADB
#undef STAGE

  // ---- acc -> LDS partials (valid C rows = tokens 0-7 at rq<2) ----
  const int rq = lane >> 4;
  if (rq < 2) {
    #pragma unroll
    for (int r = 0; r < 4; ++r) wsl[kh][rq * 4 + r][row] = acc0[r];
    if (row < 8) {
      #pragma unroll
      for (int r = 0; r < 4; ++r) wsl[kh][rq * 4 + r][16 + row] = acc1[r];
    }
  }
  // ssq: lanes l, l^16, l^32 share row -> combine the 4 k-slices
  ssq += __shfl_xor(ssq, 16, 64);
  ssq += __shfl_xor(ssq, 32, 64);
  if (ks == 0 && row < 8) wsl[kh][row][24] = ssq;
  __syncthreads();

  // ---- in-block reduce (4 kh sets) + sinkhorn: waves 0-1, 16 lanes/token ----
  if (wave < 2) {
    const int tt = wave * 4 + (lane >> 4);     // token 0..7
    const int e  = lane & 15;                  // i*4 + j
    float sres = wsl[0][tt][8 + e] + wsl[1][tt][8 + e] + wsl[2][tt][8 + e] + wsl[3][tt][8 + e];
    float ssqt = wsl[0][tt][24] + wsl[1][tt][24] + wsl[2][tt][24] + wsl[3][tt][24];
    float spre = 0.f, spost = 0.f;
    if (e < NS) {
      spre  = wsl[0][tt][e] + wsl[1][tt][e] + wsl[2][tt][e] + wsl[3][tt][e];
      spost = wsl[0][tt][NS + e] + wsl[1][tt][NS + e] + wsl[2][tt][NS + e] + wsl[3][tt][NS + e];
    }

    const float rs = rsqrtf(ssqt * (1.0f / DDIM) + NORM_EPS_F);
    const float s0 = hc_scale[0], s1 = hc_scale[1], s2 = hc_scale[2];

    float h = sres * rs * s2 + hc_base[8 + e];
    float mx = fmaxf(h, __shfl_xor(h, 1, 4));
    mx = fmaxf(mx, __shfl_xor(mx, 2, 4));
    float ex = expf(h - mx);
    float sm = ex + __shfl_xor(ex, 1, 4);
    sm += __shfl_xor(sm, 2, 4);
    h = ex * frcp(sm) + HC_EPS_F;
    float cs = h + __shfl_xor(h, 4, 16);
    cs += __shfl_xor(cs, 8, 16);
    h *= frcp(cs + HC_EPS_F);
    #pragma unroll 1
    for (int itn = 0; itn < 19; ++itn) {
      float rsum = h + __shfl_xor(h, 1, 4);
      rsum += __shfl_xor(rsum, 2, 4);
      h *= frcp(rsum + HC_EPS_F);
      float csum = h + __shfl_xor(h, 4, 16);
      csum += __shfl_xor(csum, 8, 16);
      h *= frcp(csum + HC_EPS_F);
    }
    // transposed gates: gates[m][ntok]
    gates[(size_t)(8 + e) * ntok + tok0 + tt] = h;
    if (e < NS) {
      gates[(size_t)e * ntok + tok0 + tt] =
          frcp(1.0f + expf(-(spre * rs * s0 + hc_base[e]))) + HC_EPS_F;
      gates[(size_t)(NS + e) * ntok + tok0 + tt] =
          2.0f * frcp(1.0f + expf(-(spost * rs * s1 + hc_base[NS + e])));
    }
  }
}

// ============ K2: gates + x -> out (pure stream; transposed gate reads) ============
__launch_bounds__(256, 8)
__global__ void mhc_out(const float* __restrict__ x,
                        const float* __restrict__ gates,
                        float* __restrict__ out, int ntok) {
  const long long token = blockIdx.x;
  const int q = threadIdx.x;           // float4 index in [0,256)

  float hp[NS], hq[NS], hr[NS][NS];
  #pragma unroll
  for (int i = 0; i < NS; ++i) {
    hp[i] = gates[(size_t)i * ntok + token];            // uniform scalar loads
    hq[i] = gates[(size_t)(NS + i) * ntok + token];
    #pragma unroll
    for (int j = 0; j < NS; ++j)
      hr[i][j] = gates[(size_t)(8 + i * NS + j) * ntok + token];
  }

  const float4* xb = (const float4*)(x + token * DDIM);
  float4 xv[NS];
  #pragma unroll
  for (int i = 0; i < NS; ++i) xv[i] = xb[i * 256 + q];

  float4 y;
  y.x = hp[0]*xv[0].x + hp[1]*xv[1].x + hp[2]*xv[2].x + hp[3]*xv[3].x;
  y.y = hp[0]*xv[0].y + hp[1]*xv[1].y + hp[2]*xv[2].y + hp[3]*xv[3].y;
  y.z = hp[0]*xv[0].z + hp[1]*xv[1].z + hp[2]*xv[2].z + hp[3]*xv[3].z;
  y.w = hp[0]*xv[0].w + hp[1]*xv[1].w + hp[2]*xv[2].w + hp[3]*xv[3].w;

  float4* ob = (float4*)(out + token * DDIM);
  #pragma unroll
  for (int n = 0; n < NS; ++n) {
    float4 o;
    o.x = hq[n]*y.x + hr[0][n]*xv[0].x + hr[1][n]*xv[1].x + hr[2][n]*xv[2].x + hr[3][n]*xv[3].x;
    o.y = hq[n]*y.y + hr[0][n]*xv[0].y + hr[1][n]*xv[1].y + hr[2][n]*xv[2].y + hr[3][n]*xv[3].y;
    o.z = hq[n]*y.z + hr[0][n]*xv[0].z + hr[1][n]*xv[1].z + hr[2][n]*xv[2].z + hr[3][n]*xv[3].z;
    o.w = hq[n]*y.w + hr[0][n]*xv[0].w + hr[1][n]*xv[1].w + hr[2][n]*xv[2].w + hr[3][n]*xv[3].w;
    ob[n * 256 + q] = o;
  }
}

extern "C" void kernel_launch(void* const* d_in, const int* in_sizes, int n_in,
                              void* d_out, int out_size, void* d_ws, size_t ws_size,
                              hipStream_t stream) {
  const float* x        = (const float*)d_in[0];
  const float* hc_fn    = (const float*)d_in[1];
  const float* hc_scale = (const float*)d_in[2];
  const float* hc_base  = (const float*)d_in[3];
  float* out = (float*)d_out;

  const int ntok = in_sizes[0] / DDIM;       // B*S = 8192
  float* gates = (float*)d_ws;               // 24*ntok*4 = 786432 B (PROVEN size)

  // bh/bl bf16 hi/lo live in out-scratch (K2 fully overwrites out last)
  unsigned short* bh = (unsigned short*)out;
  unsigned short* bl = bh + 24 * DDIM;

  mhc_convb<<<(24 * DDIM / 4) / 256, 256, 0, stream>>>(hc_fn, bh, bl);
  mhc_fused<<<ntok / TOK_B, 256, 0, stream>>>(x, bh, bl, hc_scale, hc_base, gates, ntok);
  mhc_out<<<ntok, 256, 0, stream>>>(x, gates, out, ntok);
}

// Round 21
// 99.889 us; speedup vs baseline: 1.3427x; 1.3427x over previous
//
#include <hip/hip_runtime.h>
#include <math.h>

#define NS 4
#define HDIM 1024
#define DDIM 4096           // NS*HDIM
#define T 4                 // tokens per block
#define NTH 512             // 8 waves
#define HC_EPS_F 1e-6f
#define NORM_EPS_F 1e-6f

__device__ __forceinline__ float frcp(float v) { return __builtin_amdgcn_rcpf(v); }

__device__ __forceinline__ void gload_lds16(const float* g, float* l) {
  __builtin_amdgcn_global_load_lds(
      (const __attribute__((address_space(1))) void*)g,
      (__attribute__((address_space(3))) void*)l, 16, 0, 0);
}

// ============ ONE-PASS: stage x once -> dots -> sinkhorn -> out. ============
// No scratch, no second x read, no partial stores, single dispatch.
// x[tok0..tok0+4) is 16384 CONTIGUOUS floats -> stage is perfectly coalesced
// and LDS layout == memory layout (no swizzle needed: all reads row-sequential).
__launch_bounds__(NTH, 2)   // cap ~128 VGPR; demand ~80. LDS 65.5 KB -> 2 blocks/CU.
__global__ void mhc_onepass(const float* __restrict__ x,
                            const float* __restrict__ hc_fn,
                            const float* __restrict__ hc_scale,
                            const float* __restrict__ hc_base,
                            float* __restrict__ out) {
  __shared__ float xs[T * DDIM];       // 64 KB
  __shared__ float w_s[25][T];         // 24 dots + ssq
  __shared__ float g_s[24][T];         // gates

  const int tid  = threadIdx.x;
  const int lane = tid & 63;
  const int wave = tid >> 6;
  const long long tok0 = (long long)blockIdx.x * T;
  const float* xg = x + tok0 * DDIM;   // contiguous 64 KB

  // ---- Phase A: stage 64 KB, 8 rounds x 512 thr x 16 B. 0 VGPR cost. ----
  #pragma unroll
  for (int c = 0; c < 8; ++c)
    gload_lds16(xg + (c * NTH + tid) * 4, xs + (size_t)(c * NTH + wave * 64) * 4);

  // fn bases for this wave's 3 m-rows (computed while stages fly)
  const int mb = wave * 3;
  const float4* fn4[3];
  #pragma unroll
  for (int m = 0; m < 3; ++m)
    fn4[m] = (const float4*)(hc_fn + (long long)(mb + m) * DDIM);

  float acc[3][T];
  #pragma unroll
  for (int m = 0; m < 3; ++m)
    #pragma unroll
    for (int t = 0; t < T; ++t) acc[m][t] = 0.f;
  float ssq = 0.f;                     // waves 0-3: ssq of token `wave`

  float4 c_fn[3];
  #pragma unroll
  for (int m = 0; m < 3; ++m) c_fn[m] = fn4[m][lane];

  __syncthreads();                     // x staged (vmcnt drained)

  // ---- Phase B: dots from LDS; fn 1-deep prefetch (L2-hot). ----
  const float4* xs4 = (const float4*)xs;
  #pragma unroll 2
  for (int it = 0; it < 16; ++it) {
    float4 n_fn[3];
    if (it < 15) {
      const int nfl = (it + 1) * 64 + lane;
      #pragma unroll
      for (int m = 0; m < 3; ++m) n_fn[m] = fn4[m][nfl];
    }
    const int fl = it * 64 + lane;
    const float4 xv0 = xs4[fl];
    const float4 xv1 = xs4[1024 + fl];
    const float4 xv2 = xs4[2048 + fl];
    const float4 xv3 = xs4[3072 + fl];

    if (wave < 4) {                    // ssq of token `wave`
      const float4 xw = (wave == 0) ? xv0 : (wave == 1) ? xv1 : (wave == 2) ? xv2 : xv3;
      ssq = fmaf(xw.x, xw.x, fmaf(xw.y, xw.y, fmaf(xw.z, xw.z, fmaf(xw.w, xw.w, ssq))));
    }
    #pragma unroll
    for (int m = 0; m < 3; ++m) {
      acc[m][0] = fmaf(xv0.x, c_fn[m].x, fmaf(xv0.y, c_fn[m].y,
                  fmaf(xv0.z, c_fn[m].z, fmaf(xv0.w, c_fn[m].w, acc[m][0]))));
      acc[m][1] = fmaf(xv1.x, c_fn[m].x, fmaf(xv1.y, c_fn[m].y,
                  fmaf(xv1.z, c_fn[m].z, fmaf(xv1.w, c_fn[m].w, acc[m][1]))));
      acc[m][2] = fmaf(xv2.x, c_fn[m].x, fmaf(xv2.y, c_fn[m].y,
                  fmaf(xv2.z, c_fn[m].z, fmaf(xv2.w, c_fn[m].w, acc[m][2]))));
      acc[m][3] = fmaf(xv3.x, c_fn[m].x, fmaf(xv3.y, c_fn[m].y,
                  fmaf(xv3.z, c_fn[m].z, fmaf(xv3.w, c_fn[m].w, acc[m][3]))));
    }
    if (it < 15) {
      #pragma unroll
      for (int m = 0; m < 3; ++m) c_fn[m] = n_fn[m];
    }
  }

  // ---- reduce: 12 values/wave (+ ssq on waves 0-3) ----
  #pragma unroll
  for (int m = 0; m < 3; ++m)
    #pragma unroll
    for (int t = 0; t < T; ++t) {
      float v = acc[m][t];
      #pragma unroll
      for (int off = 32; off > 0; off >>= 1) v += __shfl_xor(v, off, 64);
      if (lane == 0) w_s[mb + m][t] = v;
    }
  if (wave < 4) {
    float v = ssq;
    #pragma unroll
    for (int off = 32; off > 0; off >>= 1) v += __shfl_xor(v, off, 64);
    if (lane == 0) w_s[24][wave] = v;
  }
  __syncthreads();

  // ---- Phase C: sinkhorn + gates on wave 0 (lane = tt*16 + e), proven R1/R2 form ----
  if (wave == 0) {
    const int tt = lane >> 4;
    const int e  = lane & 15;          // i*4 + j
    const float rs = rsqrtf(w_s[24][tt] * (1.0f / DDIM) + NORM_EPS_F);
    const float s0 = hc_scale[0], s1 = hc_scale[1], s2 = hc_scale[2];

    float h = w_s[8 + e][tt] * rs * s2 + hc_base[8 + e];
    float mx = fmaxf(h, __shfl_xor(h, 1, 4));
    mx = fmaxf(mx, __shfl_xor(mx, 2, 4));
    float ex = expf(h - mx);
    float sm = ex + __shfl_xor(ex, 1, 4);
    sm += __shfl_xor(sm, 2, 4);
    h = ex * frcp(sm) + HC_EPS_F;
    float cs = h + __shfl_xor(h, 4, 16);
    cs += __shfl_xor(cs, 8, 16);
    h *= frcp(cs + HC_EPS_F);
    #pragma unroll 1
    for (int itn = 0; itn < 19; ++itn) {
      float rsum = h + __shfl_xor(h, 1, 4);
      rsum += __shfl_xor(rsum, 2, 4);
      h *= frcp(rsum + HC_EPS_F);
      float csum = h + __shfl_xor(h, 4, 16);
      csum += __shfl_xor(csum, 8, 16);
      h *= frcp(csum + HC_EPS_F);
    }
    g_s[8 + e][tt] = h;
    if (e < NS) {
      const float wp = w_s[e][tt] * rs;
      g_s[e][tt] = frcp(1.0f + expf(-(wp * s0 + hc_base[e]))) + HC_EPS_F;
      const float wq = w_s[NS + e][tt] * rs;
      g_s[NS + e][tt] = 2.0f * frcp(1.0f + expf(-(wq * s1 + hc_base[NS + e])));
    }
  }
  __syncthreads();

  // ---- Phase D: out from LDS-x + LDS-gates. wave -> (token tt, h-half). ----
  {
    const int tt   = wave >> 1;
    const int half = wave & 1;
    float hp[NS], hq[NS], hr[NS][NS];
    #pragma unroll
    for (int i = 0; i < NS; ++i) {
      hp[i] = g_s[i][tt];
      hq[i] = g_s[NS + i][tt];
      #pragma unroll
      for (int j = 0; j < NS; ++j) hr[i][j] = g_s[8 + i * NS + j][tt];
    }
    float4* ob = (float4*)(out + (tok0 + tt) * DDIM);
    #pragma unroll
    for (int c = 0; c < 2; ++c) {
      const int h4 = half * 128 + c * 64 + lane;   // float4-in-HDIM index [0,256)
      float4 xv[NS];
      #pragma unroll
      for (int i = 0; i < NS; ++i) xv[i] = xs4[tt * 1024 + i * 256 + h4];
      float4 y;
      y.x = hp[0]*xv[0].x + hp[1]*xv[1].x + hp[2]*xv[2].x + hp[3]*xv[3].x;
      y.y = hp[0]*xv[0].y + hp[1]*xv[1].y + hp[2]*xv[2].y + hp[3]*xv[3].y;
      y.z = hp[0]*xv[0].z + hp[1]*xv[1].z + hp[2]*xv[2].z + hp[3]*xv[3].z;
      y.w = hp[0]*xv[0].w + hp[1]*xv[1].w + hp[2]*xv[2].w + hp[3]*xv[3].w;
      #pragma unroll
      for (int n = 0; n < NS; ++n) {
        float4 o;
        o.x = hq[n]*y.x + hr[0][n]*xv[0].x + hr[1][n]*xv[1].x + hr[2][n]*xv[2].x + hr[3][n]*xv[3].x;
        o.y = hq[n]*y.y + hr[0][n]*xv[0].y + hr[1][n]*xv[1].y + hr[2][n]*xv[2].y + hr[3][n]*xv[3].y;
        o.z = hq[n]*y.z + hr[0][n]*xv[0].z + hr[1][n]*xv[1].z + hr[2][n]*xv[2].z + hr[3][n]*xv[3].z;
        o.w = hq[n]*y.w + hr[0][n]*xv[0].w + hr[1][n]*xv[1].w + hr[2][n]*xv[2].w + hr[3][n]*xv[3].w;
        ob[n * 256 + h4] = o;
      }
    }
  }
}

extern "C" void kernel_launch(void* const* d_in, const int* in_sizes, int n_in,
                              void* d_out, int out_size, void* d_ws, size_t ws_size,
                              hipStream_t stream) {
  const float* x        = (const float*)d_in[0];
  const float* hc_fn    = (const float*)d_in[1];
  const float* hc_scale = (const float*)d_in[2];
  const float* hc_base  = (const float*)d_in[3];
  float* out = (float*)d_out;

  const int ntok = in_sizes[0] / DDIM;   // B*S = 8192
  mhc_onepass<<<ntok / T, NTH, 0, stream>>>(x, hc_fn, hc_scale, hc_base, out);
}